// Round 1
// baseline (1005.203 us; speedup 1.0000x reference)
//
#include <hip/hip_runtime.h>
#include <math.h>

#define T_DATA 50000
#define E_NO   2000
#define I_NO   500
#define SUBN   20
#define MN     8
#define KLEN   200
#define TILE   512
#define HALO   199
#define TW     712   // 711 used + 1 pad

// ---------------------------------------------------------------------------
// fast transcendentals (tolerance headroom: absmax 0.031 vs 0.1725 threshold)
// ---------------------------------------------------------------------------
__device__ __forceinline__ float fast_tanh(float x) {
  float ax = fabsf(x);
  float e  = __expf(-2.f * ax);                       // v_exp_f32 path
  float r  = __builtin_amdgcn_rcpf(1.f + e);          // v_rcp_f32
  float t  = fmaf(-2.f * e, r, 1.f);                  // (1-e)/(1+e)
  return copysignf(t, x);
}

// ---------------------------------------------------------------------------
// 4-tap x 4-output conv micro-tile.
// acc[r] += k[j] * w[r+3-j],  w[q] = x[S+q], L = x[S..S+3], H = x[S+4..S+7]
// ---------------------------------------------------------------------------
__device__ __forceinline__ void conv4(float acc[4], const float4 L,
                                      const float4 H, const float4 k4) {
  const float w0 = L.x, w1 = L.y, w2 = L.z, w3 = L.w;
  const float w4 = H.x, w5 = H.y, w6 = H.z;
  acc[0] += k4.x * w3; acc[1] += k4.x * w4; acc[2] += k4.x * w5; acc[3] += k4.x * w6;
  acc[0] += k4.y * w2; acc[1] += k4.y * w3; acc[2] += k4.y * w4; acc[3] += k4.y * w5;
  acc[0] += k4.z * w1; acc[1] += k4.z * w2; acc[2] += k4.z * w3; acc[3] += k4.z * w4;
  acc[0] += k4.w * w0; acc[1] += k4.w * w1; acc[2] += k4.w * w2; acc[3] += k4.w * w3;
}

// ---------------------------------------------------------------------------
// Routing + (fused) kernel precompute.
// blocks [0,12500): Se[s][t] = sum_{j%20==s} S_e[t][j]  (same for Si)
// blocks [12500,12600): k_r[row][d] = sum_b W[row,b]*bases[b,199-d]
// ---------------------------------------------------------------------------
__global__ __launch_bounds__(320) void route_kernel(
    const float* __restrict__ S_e, const float* __restrict__ S_i,
    float* __restrict__ Se, float* __restrict__ Si,
    const float* __restrict__ we, const float* __restrict__ be,
    const float* __restrict__ wi, const float* __restrict__ bi,
    const float* __restrict__ w2, const float* __restrict__ b2,
    float* __restrict__ k1e, float* __restrict__ k1i, float* __restrict__ k2) {
  __shared__ float lds_e[1280];
  __shared__ float lds_i[500];
  int tid = threadIdx.x;
  int bid = blockIdx.x;

  if (bid >= 12500) {   // precompute tail blocks
    int idx = (bid - 12500) * 320 + tid;
    if (idx < 160 * KLEN) {
      int row = idx / KLEN, d = idx % KLEN;
      int col = KLEN - 1 - d;
      float se = 0.f, si = 0.f, s2 = 0.f;
#pragma unroll
      for (int b = 0; b < 12; ++b) {
        se += we[row * 12 + b] * be[b * KLEN + col];
        si += wi[row * 12 + b] * bi[b * KLEN + col];
        s2 += w2[row * 12 + b] * b2[b * KLEN + col];
      }
      k1e[idx] = se; k1i[idx] = si; k2[idx] = s2;
    }
    return;
  }

  int t0 = bid * 4;
  for (int tt = 0; tt < 4; ++tt) {
    int t = t0 + tt;
    const float4* rowE = (const float4*)(S_e + (size_t)t * E_NO);
    float4 a = rowE[tid];
    if (tid < 180) {
      float4 b = rowE[tid + 320];
      a.x += b.x; a.y += b.y; a.z += b.z; a.w += b.w;
    }
    ((float4*)lds_e)[tid] = a;
    if (tid < 125) {
      const float4* rowI = (const float4*)(S_i + (size_t)t * I_NO);
      ((float4*)lds_i)[tid] = rowI[tid];
    }
    __syncthreads();
    if (tid < 20) {
      float s = 0.f;
#pragma unroll
      for (int k = 0; k < 64; ++k) s += lds_e[tid + 20 * k];
      Se[tid * T_DATA + t] = s;
    } else if (tid >= 64 && tid < 84) {
      int r = tid - 64;
      float s = 0.f;
#pragma unroll
      for (int k = 0; k < 25; ++k) s += lds_i[r + 20 * k];
      Si[r * T_DATA + t] = s;
    }
    __syncthreads();
  }
}

// ---------------------------------------------------------------------------
// conv1: Sconv[s*8+m][t] = sum_d k1e_r[..][d]*Se[s][t-d] + k1i_r[..][d]*Si[s][t-d]
// Lane mapping: outputs u = 4g + 128*i + r -> lane word-stride 4, conflict-free.
// ---------------------------------------------------------------------------
__global__ __launch_bounds__(256) void conv1_kernel(
    const float* __restrict__ Se, const float* __restrict__ Si,
    const float* __restrict__ k1e, const float* __restrict__ k1i,
    float* __restrict__ Sconv) {
  __shared__ float xe_raw[TW + 4], xi_raw[TW + 4];
  __shared__ float ke[MN * KLEN], ki[MN * KLEN];
  float* xe = xe_raw + 4;   // front pad: last-iter prefetch reads index -4
  float* xi = xi_raw + 4;
  int s = blockIdx.y;
  int t0 = blockIdx.x * TILE;
  int tid = threadIdx.x;

  for (int idx = tid; idx < TW; idx += 256) {
    int t = t0 - HALO + idx;
    bool ok = (t >= 0) && (t < T_DATA) && (idx < 711);
    xe[idx] = ok ? Se[s * T_DATA + t] : 0.f;
    xi[idx] = ok ? Si[s * T_DATA + t] : 0.f;
  }
  for (int idx = tid; idx < MN * KLEN; idx += 256) {
    ke[idx] = k1e[s * MN * KLEN + idx];
    ki[idx] = k1i[s * MN * KLEN + idx];
  }
  __syncthreads();

  int m = tid >> 5, g = tid & 31;
  const float* kem = ke + m * KLEN;
  const float* kim = ki + m * KLEN;
  float* outp = Sconv + ((size_t)(s * MN + m)) * T_DATA + t0;

#pragma unroll 1
  for (int i = 0; i < 4; ++i) {
    const int U = 4 * g + 128 * i;
    const int S0 = U + 196;
    float4 Le = *(const float4*)(xe + S0);
    float4 He = *(const float4*)(xe + S0 + 4);
    float4 Lx = *(const float4*)(xi + S0);
    float4 Hx = *(const float4*)(xi + S0 + 4);
    float acc[4] = {0.f, 0.f, 0.f, 0.f};
    for (int d0 = 0; d0 < KLEN; d0 += 8) {
      float4 ka = *(const float4*)(kem + d0);
      float4 kb = *(const float4*)(kim + d0);
      conv4(acc, Le, He, ka);
      conv4(acc, Lx, Hx, kb);
      float4 Ne = *(const float4*)(xe + S0 - d0 - 4);
      float4 Nx = *(const float4*)(xi + S0 - d0 - 4);
      ka = *(const float4*)(kem + d0 + 4);
      kb = *(const float4*)(kim + d0 + 4);
      conv4(acc, Ne, Le, ka);
      conv4(acc, Nx, Lx, kb);
      He = Ne; Le = *(const float4*)(xe + S0 - d0 - 8);
      Hx = Nx; Lx = *(const float4*)(xi + S0 - d0 - 8);
    }
    if (t0 + U < T_DATA)
      *(float4*)(outp + U) = make_float4(acc[0], acc[1], acc[2], acc[3]);
  }
}

// ---------------------------------------------------------------------------
// Level kernel, templated on time-tile (occupancy for small tree levels)
// ---------------------------------------------------------------------------
struct LevelArgs {
  int node[8];
  int c1[8];
  int c2[8];
};

template <int LT>
__global__ __launch_bounds__(256) void level_kernel(
    const float* __restrict__ Sconv, const float* __restrict__ k2r,
    const float* __restrict__ leaf_lin, const float* __restrict__ mult_lin,
    const float* __restrict__ mult_bias, float* __restrict__ sub_out,
    float* __restrict__ d_out, LevelArgs args) {
  const int TWL = LT + KLEN;                 // LT+199 used + 1 pad
  __shared__ float hbuf_raw[4 + MN * (LT + KLEN)];
  __shared__ float k2l[MN * KLEN];
  __shared__ float red[MN * LT];
  float* hbuf = hbuf_raw + 4;
  int tid = threadIdx.x;
  int t0 = blockIdx.x * LT;
  int ni = blockIdx.y;
  int p = args.node[ni], c1 = args.c1[ni], c2 = args.c2[ni];

  for (int idx = tid; idx < MN * KLEN; idx += 256)
    k2l[idx] = k2r[p * MN * KLEN + idx];

  // h = tanh(Sconv + expL1*child1 + expL2*child2) over tile + halo
  for (int m = 0; m < MN; ++m) {
    float eL1 = (c1 >= 0) ? __expf(leaf_lin[c1 * MN + m]) : 0.f;
    float eL2 = (c2 >= 0) ? __expf(leaf_lin[c2 * MN + m]) : 0.f;
    const float* scp = Sconv + ((size_t)(p * MN + m)) * T_DATA;
    const float* s1 = sub_out + (size_t)((c1 >= 0) ? c1 : 0) * T_DATA;
    const float* s2 = sub_out + (size_t)((c2 >= 0) ? c2 : 0) * T_DATA;
    for (int idx = tid; idx < TWL; idx += 256) {
      int t = t0 - HALO + idx;
      float v = 0.f;
      if (t >= 0 && t < T_DATA && idx < TWL - 1) {
        float x = scp[t];
        if (c1 >= 0) x += eL1 * s1[t];
        if (c2 >= 0) x += eL2 * s2[t];
        v = fast_tanh(x);
      }
      hbuf[m * TWL + idx] = v;
    }
  }
  __syncthreads();

  // depthwise causal conv-200, conflict-free lane mapping + sliding window
  int m = tid >> 5, g = tid & 31;
  const float* km = k2l + m * KLEN;
  const float* hm = hbuf + m * TWL;
  float eM = __expf(mult_lin[p * MN + m]);

#pragma unroll 1
  for (int i = 0; i < LT / 128; ++i) {
    const int U = 4 * g + 128 * i;
    const int S0 = U + 196;
    float4 L = *(const float4*)(hm + S0);
    float4 H = *(const float4*)(hm + S0 + 4);
    float acc[4] = {0.f, 0.f, 0.f, 0.f};
    for (int d0 = 0; d0 < KLEN; d0 += 8) {
      float4 ka = *(const float4*)(km + d0);
      conv4(acc, L, H, ka);
      float4 N = *(const float4*)(hm + S0 - d0 - 4);
      ka = *(const float4*)(km + d0 + 4);
      conv4(acc, N, L, ka);
      H = N; L = *(const float4*)(hm + S0 - d0 - 8);
    }
    *(float4*)(red + m * LT + U) =
        make_float4(fast_tanh(acc[0]) * eM, fast_tanh(acc[1]) * eM,
                    fast_tanh(acc[2]) * eM, fast_tanh(acc[3]) * eM);
  }
  __syncthreads();

  // reduce over m, add bias, write
  float bias = mult_bias[p];
  float* outp = (p == 0) ? d_out : (sub_out + (size_t)p * T_DATA);
#pragma unroll
  for (int k = 0; k < (LT + 255) / 256; ++k) {
    int tl2 = tid + k * 256;
    if (tl2 < LT) {
      int t = t0 + tl2;
      if (t < T_DATA) {
        float ssum = bias;
#pragma unroll
        for (int mm = 0; mm < MN; ++mm) ssum += red[mm * LT + tl2];
        outp[t] = ssum;
      }
    }
  }
}

// ---------------------------------------------------------------------------
extern "C" void kernel_launch(void* const* d_in, const int* in_sizes, int n_in,
                              void* d_out, int out_size, void* d_ws, size_t ws_size,
                              hipStream_t stream) {
  const float* S_e  = (const float*)d_in[0];
  const float* S_i  = (const float*)d_in[1];
  const float* c1eb = (const float*)d_in[5];
  const float* c1ew = (const float*)d_in[6];
  const float* c1ib = (const float*)d_in[7];
  const float* c1iw = (const float*)d_in[8];
  const float* c2b  = (const float*)d_in[9];
  const float* c2w  = (const float*)d_in[10];
  const float* ll   = (const float*)d_in[11];
  const float* ml   = (const float*)d_in[12];
  const float* mb   = (const float*)d_in[13];

  float* ws    = (float*)d_ws;
  float* Se    = ws;                 // 1,000,000
  float* Si    = ws + 1000000;       // 1,000,000
  float* Sconv = ws + 2000000;       // 8,000,000
  float* subo  = ws + 10000000;      // 1,000,000
  float* k1e   = ws + 11000000;      // 32,000
  float* k1i   = k1e + 32000;        // 32,000
  float* k2    = k1i + 32000;        // 32,000
  float* out   = (float*)d_out;

  // routing + kernel precompute fused (12500 route blocks + 100 precompute)
  route_kernel<<<dim3(12600), 320, 0, stream>>>(S_e, S_i, Se, Si,
                                                c1ew, c1eb, c1iw, c1ib, c2w, c2b,
                                                k1e, k1i, k2);

  conv1_kernel<<<dim3(98, SUBN), 256, 0, stream>>>(Se, Si, k1e, k1i, Sconv);

  LevelArgs L4 = {{15, 16, 17, 18, 19, 0, 0, 0},
                  {-1, -1, -1, -1, -1, 0, 0, 0},
                  {-1, -1, -1, -1, -1, 0, 0, 0}};
  LevelArgs L3 = {{7, 8, 9, 10, 11, 12, 13, 14},
                  {15, 17, 19, -1, -1, -1, -1, -1},
                  {16, 18, -1, -1, -1, -1, -1, -1}};
  LevelArgs L2 = {{3, 4, 5, 6, 0, 0, 0, 0},
                  {7, 9, 11, 13, 0, 0, 0, 0},
                  {8, 10, 12, 14, 0, 0, 0, 0}};
  LevelArgs L1 = {{1, 2, 0, 0, 0, 0, 0, 0},
                  {3, 5, 0, 0, 0, 0, 0, 0},
                  {4, 6, 0, 0, 0, 0, 0, 0}};
  LevelArgs L0 = {{0, 0, 0, 0, 0, 0, 0, 0},
                  {1, 0, 0, 0, 0, 0, 0, 0},
                  {2, 0, 0, 0, 0, 0, 0, 0}};

  // big levels: TILE 256 (196 tiles); small levels: TILE 128 (391 tiles)
  level_kernel<256><<<dim3(196, 5), 256, 0, stream>>>(Sconv, k2, ll, ml, mb, subo, out, L4);
  level_kernel<256><<<dim3(196, 8), 256, 0, stream>>>(Sconv, k2, ll, ml, mb, subo, out, L3);
  level_kernel<128><<<dim3(391, 4), 256, 0, stream>>>(Sconv, k2, ll, ml, mb, subo, out, L2);
  level_kernel<128><<<dim3(391, 2), 256, 0, stream>>>(Sconv, k2, ll, ml, mb, subo, out, L1);
  level_kernel<128><<<dim3(391, 1), 256, 0, stream>>>(Sconv, k2, ll, ml, mb, subo, out, L0);
}

// Round 2
// 999.580 us; speedup vs baseline: 1.0056x; 1.0056x over previous
//
#include <hip/hip_runtime.h>
#include <math.h>

#define T_DATA 50000
#define E_NO   2000
#define I_NO   500
#define SUBN   20
#define MN     8
#define KLEN   200
#define TILE   512
#define HALO   199
#define TW     712   // 711 used + 1 pad

// ---------------------------------------------------------------------------
// fast transcendentals (tolerance headroom: absmax 0.031 vs 0.1725 threshold)
// ---------------------------------------------------------------------------
__device__ __forceinline__ float fast_tanh(float x) {
  float ax = fabsf(x);
  float e  = __expf(-2.f * ax);                       // v_exp_f32 path
  float r  = __builtin_amdgcn_rcpf(1.f + e);          // v_rcp_f32
  float t  = fmaf(-2.f * e, r, 1.f);                  // (1-e)/(1+e)
  return copysignf(t, x);
}

// ---------------------------------------------------------------------------
// 4-tap x 4-output conv micro-tile.
// acc[r] += k[j] * w[r+3-j],  w[q] = x[S+q], L = x[S..S+3], H = x[S+4..S+7]
// ---------------------------------------------------------------------------
__device__ __forceinline__ void conv4(float acc[4], const float4 L,
                                      const float4 H, const float4 k4) {
  const float w0 = L.x, w1 = L.y, w2 = L.z, w3 = L.w;
  const float w4 = H.x, w5 = H.y, w6 = H.z;
  acc[0] += k4.x * w3; acc[1] += k4.x * w4; acc[2] += k4.x * w5; acc[3] += k4.x * w6;
  acc[0] += k4.y * w2; acc[1] += k4.y * w3; acc[2] += k4.y * w4; acc[3] += k4.y * w5;
  acc[0] += k4.z * w1; acc[1] += k4.z * w2; acc[2] += k4.z * w3; acc[3] += k4.z * w4;
  acc[0] += k4.w * w0; acc[1] += k4.w * w1; acc[2] += k4.w * w2; acc[3] += k4.w * w3;
}

// ---------------------------------------------------------------------------
// Routing + (fused) kernel precompute.
// blocks [0,12500): Se[s][t] = sum_{j%20==s} S_e[t][j]  (same for Si)
// blocks [12500,12600): k_r[row][d] = sum_b W[row,b]*bases[b,199-d]
// v2: stage all 4 timesteps, ONE sync, 320-lane parallel reduction.
// ---------------------------------------------------------------------------
__global__ __launch_bounds__(320) void route_kernel(
    const float* __restrict__ S_e, const float* __restrict__ S_i,
    float* __restrict__ Se, float* __restrict__ Si,
    const float* __restrict__ we, const float* __restrict__ be,
    const float* __restrict__ wi, const float* __restrict__ bi,
    const float* __restrict__ w2, const float* __restrict__ b2,
    float* __restrict__ k1e, float* __restrict__ k1i, float* __restrict__ k2) {
  __shared__ float lds_e[4 * 1280];
  __shared__ float lds_i[4 * 500];
  int tid = threadIdx.x;
  int bid = blockIdx.x;

  if (bid >= 12500) {   // precompute tail blocks
    int idx = (bid - 12500) * 320 + tid;
    if (idx < 160 * KLEN) {
      int row = idx / KLEN, d = idx % KLEN;
      int col = KLEN - 1 - d;
      float se = 0.f, si = 0.f, s2 = 0.f;
#pragma unroll
      for (int b = 0; b < 12; ++b) {
        se += we[row * 12 + b] * be[b * KLEN + col];
        si += wi[row * 12 + b] * bi[b * KLEN + col];
        s2 += w2[row * 12 + b] * b2[b * KLEN + col];
      }
      k1e[idx] = se; k1i[idx] = si; k2[idx] = s2;
    }
    return;
  }

  int t0 = bid * 4;
#pragma unroll
  for (int tt = 0; tt < 4; ++tt) {
    int t = t0 + tt;
    const float4* rowE = (const float4*)(S_e + (size_t)t * E_NO);
    float4 a = rowE[tid];
    if (tid < 180) {
      float4 b = rowE[tid + 320];
      a.x += b.x; a.y += b.y; a.z += b.z; a.w += b.w;
    }
    ((float4*)(lds_e + tt * 1280))[tid] = a;
    if (tid < 125) {
      const float4* rowI = (const float4*)(S_i + (size_t)t * I_NO);
      ((float4*)(lds_i + tt * 500))[tid] = rowI[tid];
    }
  }
  __syncthreads();

  // 80 (t,s) pairs x 4 lanes; lane j sums k = 4i+j (stride-4 interleave:
  // bank offsets 20j % 32 = {0,20,8,28} -> distinct, conflicts <= 2-way (free))
  int p = tid >> 2, j = tid & 3;       // p in 0..79
  int tt = p / 20, s = p % 20;
  const float* le = lds_e + tt * 1280 + s;
  const float* li = lds_i + tt * 500 + s;
  float se = 0.f;
#pragma unroll
  for (int i = 0; i < 16; ++i) se += le[20 * (4 * i + j)];
  float sv = 0.f;
#pragma unroll
  for (int i = 0; i < 7; ++i) {
    int k = 4 * i + j;
    if (k < 25) sv += li[20 * k];
  }
  se += __shfl_xor(se, 1); se += __shfl_xor(se, 2);
  sv += __shfl_xor(sv, 1); sv += __shfl_xor(sv, 2);
  if (j == 0)      Se[s * T_DATA + t0 + tt] = se;
  else if (j == 1) Si[s * T_DATA + t0 + tt] = sv;
}

// ---------------------------------------------------------------------------
// conv1: Sconv[s*8+m][t] = sum_d k1e_r[..][d]*Se[s][t-d] + k1i_r[..][d]*Si[s][t-d]
// v2: each thread owns 4 output tiles (U = 4g + 128i, i=0..3) and shares the
// kernel-tap LDS loads across all 4 -> 20 b128/chunk instead of 32.
// Lane word-stride 4 -> conflict-free ds_read_b128.
// ---------------------------------------------------------------------------
__global__ __launch_bounds__(256) void conv1_kernel(
    const float* __restrict__ Se, const float* __restrict__ Si,
    const float* __restrict__ k1e, const float* __restrict__ k1i,
    float* __restrict__ Sconv) {
  __shared__ float xe_raw[TW + 4], xi_raw[TW + 4];
  __shared__ float ke[MN * KLEN], ki[MN * KLEN];
  float* xe = xe_raw + 4;   // front pad: last-iter prefetch reads index -4
  float* xi = xi_raw + 4;
  int s = blockIdx.y;
  int t0 = blockIdx.x * TILE;
  int tid = threadIdx.x;

  for (int idx = tid; idx < TW; idx += 256) {
    int t = t0 - HALO + idx;
    bool ok = (t >= 0) && (t < T_DATA) && (idx < 711);
    xe[idx] = ok ? Se[s * T_DATA + t] : 0.f;
    xi[idx] = ok ? Si[s * T_DATA + t] : 0.f;
  }
  for (int idx = tid; idx < MN * KLEN; idx += 256) {
    ke[idx] = k1e[s * MN * KLEN + idx];
    ki[idx] = k1i[s * MN * KLEN + idx];
  }
  __syncthreads();

  int m = tid >> 5, g = tid & 31;
  const float* kem = ke + m * KLEN;
  const float* kim = ki + m * KLEN;
  float* outp = Sconv + ((size_t)(s * MN + m)) * T_DATA + t0;

  float4 Le[4], He[4], Lx[4], Hx[4];
  float acc[4][4];
#pragma unroll
  for (int i = 0; i < 4; ++i) {
    const int S0 = 4 * g + 128 * i + 196;
    Le[i] = *(const float4*)(xe + S0);
    He[i] = *(const float4*)(xe + S0 + 4);
    Lx[i] = *(const float4*)(xi + S0);
    Hx[i] = *(const float4*)(xi + S0 + 4);
    acc[i][0] = acc[i][1] = acc[i][2] = acc[i][3] = 0.f;
  }

  for (int d0 = 0; d0 < KLEN; d0 += 8) {
    float4 ka0 = *(const float4*)(kem + d0);
    float4 kb0 = *(const float4*)(kim + d0);
    float4 ka1 = *(const float4*)(kem + d0 + 4);
    float4 kb1 = *(const float4*)(kim + d0 + 4);
#pragma unroll
    for (int i = 0; i < 4; ++i) {
      const int S0 = 4 * g + 128 * i + 196;
      conv4(acc[i], Le[i], He[i], ka0);
      conv4(acc[i], Lx[i], Hx[i], kb0);
      float4 Ne = *(const float4*)(xe + S0 - d0 - 4);
      float4 Nx = *(const float4*)(xi + S0 - d0 - 4);
      conv4(acc[i], Ne, Le[i], ka1);
      conv4(acc[i], Nx, Lx[i], kb1);
      He[i] = Ne; Le[i] = *(const float4*)(xe + S0 - d0 - 8);
      Hx[i] = Nx; Lx[i] = *(const float4*)(xi + S0 - d0 - 8);
    }
  }

#pragma unroll
  for (int i = 0; i < 4; ++i) {
    const int U = 4 * g + 128 * i;
    if (t0 + U < T_DATA)
      *(float4*)(outp + U) = make_float4(acc[i][0], acc[i][1], acc[i][2], acc[i][3]);
  }
}

// ---------------------------------------------------------------------------
// Level kernel, templated on time-tile (occupancy for small tree levels)
// v2: NT = LT/128 output tiles per thread share the kernel-tap loads.
// ---------------------------------------------------------------------------
struct LevelArgs {
  int node[10];
  int c1[10];
  int c2[10];
};

template <int LT>
__global__ __launch_bounds__(256) void level_kernel(
    const float* __restrict__ Sconv, const float* __restrict__ k2r,
    const float* __restrict__ leaf_lin, const float* __restrict__ mult_lin,
    const float* __restrict__ mult_bias, float* __restrict__ sub_out,
    float* __restrict__ d_out, LevelArgs args) {
  const int TWL = LT + KLEN;                 // LT+199 used + 1 pad
  constexpr int NT = LT / 128;
  __shared__ float hbuf_raw[4 + MN * (LT + KLEN)];
  __shared__ float k2l[MN * KLEN];
  __shared__ float red[MN * LT];
  float* hbuf = hbuf_raw + 4;
  int tid = threadIdx.x;
  int t0 = blockIdx.x * LT;
  int ni = blockIdx.y;
  int p = args.node[ni], c1 = args.c1[ni], c2 = args.c2[ni];

  for (int idx = tid; idx < MN * KLEN; idx += 256)
    k2l[idx] = k2r[p * MN * KLEN + idx];

  // h = tanh(Sconv + expL1*child1 + expL2*child2) over tile + halo
  for (int m = 0; m < MN; ++m) {
    float eL1 = (c1 >= 0) ? __expf(leaf_lin[c1 * MN + m]) : 0.f;
    float eL2 = (c2 >= 0) ? __expf(leaf_lin[c2 * MN + m]) : 0.f;
    const float* scp = Sconv + ((size_t)(p * MN + m)) * T_DATA;
    const float* s1 = sub_out + (size_t)((c1 >= 0) ? c1 : 0) * T_DATA;
    const float* s2 = sub_out + (size_t)((c2 >= 0) ? c2 : 0) * T_DATA;
    for (int idx = tid; idx < TWL; idx += 256) {
      int t = t0 - HALO + idx;
      float v = 0.f;
      if (t >= 0 && t < T_DATA && idx < TWL - 1) {
        float x = scp[t];
        if (c1 >= 0) x += eL1 * s1[t];
        if (c2 >= 0) x += eL2 * s2[t];
        v = fast_tanh(x);
      }
      hbuf[m * TWL + idx] = v;
    }
  }
  __syncthreads();

  // depthwise causal conv-200, conflict-free lane mapping + sliding window
  int m = tid >> 5, g = tid & 31;
  const float* km = k2l + m * KLEN;
  const float* hm = hbuf + m * TWL;
  float eM = __expf(mult_lin[p * MN + m]);

  float4 L[NT], H[NT];
  float acc[NT][4];
#pragma unroll
  for (int i = 0; i < NT; ++i) {
    const int S0 = 4 * g + 128 * i + 196;
    L[i] = *(const float4*)(hm + S0);
    H[i] = *(const float4*)(hm + S0 + 4);
    acc[i][0] = acc[i][1] = acc[i][2] = acc[i][3] = 0.f;
  }
  for (int d0 = 0; d0 < KLEN; d0 += 8) {
    float4 ka0 = *(const float4*)(km + d0);
    float4 ka1 = *(const float4*)(km + d0 + 4);
#pragma unroll
    for (int i = 0; i < NT; ++i) {
      const int S0 = 4 * g + 128 * i + 196;
      conv4(acc[i], L[i], H[i], ka0);
      float4 N = *(const float4*)(hm + S0 - d0 - 4);
      conv4(acc[i], N, L[i], ka1);
      H[i] = N; L[i] = *(const float4*)(hm + S0 - d0 - 8);
    }
  }
#pragma unroll
  for (int i = 0; i < NT; ++i) {
    const int U = 4 * g + 128 * i;
    *(float4*)(red + m * LT + U) =
        make_float4(fast_tanh(acc[i][0]) * eM, fast_tanh(acc[i][1]) * eM,
                    fast_tanh(acc[i][2]) * eM, fast_tanh(acc[i][3]) * eM);
  }
  __syncthreads();

  // reduce over m, add bias, write
  float bias = mult_bias[p];
  float* outp = (p == 0) ? d_out : (sub_out + (size_t)p * T_DATA);
#pragma unroll
  for (int k = 0; k < (LT + 255) / 256; ++k) {
    int tl2 = tid + k * 256;
    if (tl2 < LT) {
      int t = t0 + tl2;
      if (t < T_DATA) {
        float ssum = bias;
#pragma unroll
        for (int mm = 0; mm < MN; ++mm) ssum += red[mm * LT + tl2];
        outp[t] = ssum;
      }
    }
  }
}

// ---------------------------------------------------------------------------
extern "C" void kernel_launch(void* const* d_in, const int* in_sizes, int n_in,
                              void* d_out, int out_size, void* d_ws, size_t ws_size,
                              hipStream_t stream) {
  const float* S_e  = (const float*)d_in[0];
  const float* S_i  = (const float*)d_in[1];
  const float* c1eb = (const float*)d_in[5];
  const float* c1ew = (const float*)d_in[6];
  const float* c1ib = (const float*)d_in[7];
  const float* c1iw = (const float*)d_in[8];
  const float* c2b  = (const float*)d_in[9];
  const float* c2w  = (const float*)d_in[10];
  const float* ll   = (const float*)d_in[11];
  const float* ml   = (const float*)d_in[12];
  const float* mb   = (const float*)d_in[13];

  float* ws    = (float*)d_ws;
  float* Se    = ws;                 // 1,000,000
  float* Si    = ws + 1000000;       // 1,000,000
  float* Sconv = ws + 2000000;       // 8,000,000
  float* subo  = ws + 10000000;      // 1,000,000
  float* k1e   = ws + 11000000;      // 32,000
  float* k1i   = k1e + 32000;        // 32,000
  float* k2    = k1i + 32000;        // 32,000
  float* out   = (float*)d_out;

  // routing + kernel precompute fused (12500 route blocks + 100 precompute)
  route_kernel<<<dim3(12600), 320, 0, stream>>>(S_e, S_i, Se, Si,
                                                c1ew, c1eb, c1iw, c1ib, c2w, c2b,
                                                k1e, k1i, k2);

  conv1_kernel<<<dim3(98, SUBN), 256, 0, stream>>>(Se, Si, k1e, k1i, Sconv);

  // Stage A: ALL dependency-free leaves (10 nodes -> 1960 blocks, fat launch)
  LevelArgs LA = {{10, 11, 12, 13, 14, 15, 16, 17, 18, 19},
                  {-1, -1, -1, -1, -1, -1, -1, -1, -1, -1},
                  {-1, -1, -1, -1, -1, -1, -1, -1, -1, -1}};
  // Stage B: depth-3 inner nodes (need 15..19)
  LevelArgs LB = {{7, 8, 9, 0, 0, 0, 0, 0, 0, 0},
                  {15, 17, 19, 0, 0, 0, 0, 0, 0, 0},
                  {16, 18, -1, 0, 0, 0, 0, 0, 0, 0}};
  LevelArgs LC = {{3, 4, 5, 6, 0, 0, 0, 0, 0, 0},
                  {7, 9, 11, 13, 0, 0, 0, 0, 0, 0},
                  {8, 10, 12, 14, 0, 0, 0, 0, 0, 0}};
  LevelArgs LD = {{1, 2, 0, 0, 0, 0, 0, 0, 0, 0},
                  {3, 5, 0, 0, 0, 0, 0, 0, 0, 0},
                  {4, 6, 0, 0, 0, 0, 0, 0, 0, 0}};
  LevelArgs LE = {{0, 0, 0, 0, 0, 0, 0, 0, 0, 0},
                  {1, 0, 0, 0, 0, 0, 0, 0, 0, 0},
                  {2, 0, 0, 0, 0, 0, 0, 0, 0, 0}};

  level_kernel<256><<<dim3(196, 10), 256, 0, stream>>>(Sconv, k2, ll, ml, mb, subo, out, LA);
  level_kernel<256><<<dim3(196, 3),  256, 0, stream>>>(Sconv, k2, ll, ml, mb, subo, out, LB);
  level_kernel<128><<<dim3(391, 4),  256, 0, stream>>>(Sconv, k2, ll, ml, mb, subo, out, LC);
  level_kernel<128><<<dim3(391, 2),  256, 0, stream>>>(Sconv, k2, ll, ml, mb, subo, out, LD);
  level_kernel<128><<<dim3(391, 1),  256, 0, stream>>>(Sconv, k2, ll, ml, mb, subo, out, LE);
}

// Round 3
// 969.523 us; speedup vs baseline: 1.0368x; 1.0310x over previous
//
#include <hip/hip_runtime.h>
#include <math.h>

#define T_DATA 50000
#define E_NO   2000
#define I_NO   500
#define SUBN   20
#define MN     8
#define KLEN   200
#define TILE   512
#define HALO   199
#define TW     712   // 711 used + 1 pad

// ---------------------------------------------------------------------------
// fast transcendentals (tolerance headroom: absmax 0.031 vs 0.1725 threshold)
// ---------------------------------------------------------------------------
__device__ __forceinline__ float fast_tanh(float x) {
  float ax = fabsf(x);
  float e  = __expf(-2.f * ax);                       // v_exp_f32 path
  float r  = __builtin_amdgcn_rcpf(1.f + e);          // v_rcp_f32
  float t  = fmaf(-2.f * e, r, 1.f);                  // (1-e)/(1+e)
  return copysignf(t, x);
}

// ---------------------------------------------------------------------------
// 4-tap x 4-output conv micro-tile.
// acc[r] += k[j] * w[r+3-j],  w[q] = x[S+q], L = x[S..S+3], H = x[S+4..S+7]
// ---------------------------------------------------------------------------
__device__ __forceinline__ void conv4(float acc[4], const float4 L,
                                      const float4 H, const float4 k4) {
  const float w0 = L.x, w1 = L.y, w2 = L.z, w3 = L.w;
  const float w4 = H.x, w5 = H.y, w6 = H.z;
  acc[0] += k4.x * w3; acc[1] += k4.x * w4; acc[2] += k4.x * w5; acc[3] += k4.x * w6;
  acc[0] += k4.y * w2; acc[1] += k4.y * w3; acc[2] += k4.y * w4; acc[3] += k4.y * w5;
  acc[0] += k4.z * w1; acc[1] += k4.z * w2; acc[2] += k4.z * w3; acc[3] += k4.z * w4;
  acc[0] += k4.w * w0; acc[1] += k4.w * w1; acc[2] += k4.w * w2; acc[3] += k4.w * w3;
}

// Shifted aligned quad read: returns {src[t], src[t+1], src[t+2], src[t+3]}
// where t = tq and tq-1 is 16B-aligned (tq ≡ 1 mod 4). Caller guarantees
// tq-1 >= 0 and tq+6 within allocation.
__device__ __forceinline__ float4 shifted_quad(const float* __restrict__ src,
                                               int tq) {
  float4 A = *(const float4*)(src + tq - 1);
  float4 B = *(const float4*)(src + tq + 3);
  return make_float4(A.y, A.z, A.w, B.x);
}

// ---------------------------------------------------------------------------
// Routing + (fused) kernel precompute.
// blocks [0,12500): Se[s][t] = sum_{j%20==s} S_e[t][j]  (same for Si)
// blocks [12500,12600): k_r[row][d] = sum_b W[row,b]*bases[b,199-d]
// ---------------------------------------------------------------------------
__global__ __launch_bounds__(320) void route_kernel(
    const float* __restrict__ S_e, const float* __restrict__ S_i,
    float* __restrict__ Se, float* __restrict__ Si,
    const float* __restrict__ we, const float* __restrict__ be,
    const float* __restrict__ wi, const float* __restrict__ bi,
    const float* __restrict__ w2, const float* __restrict__ b2,
    float* __restrict__ k1e, float* __restrict__ k1i, float* __restrict__ k2) {
  __shared__ __align__(16) float lds_e[4 * 1280];
  __shared__ __align__(16) float lds_i[4 * 500];
  int tid = threadIdx.x;
  int bid = blockIdx.x;

  if (bid >= 12500) {   // precompute tail blocks
    int idx = (bid - 12500) * 320 + tid;
    if (idx < 160 * KLEN) {
      int row = idx / KLEN, d = idx % KLEN;
      int col = KLEN - 1 - d;
      float se = 0.f, si = 0.f, s2 = 0.f;
#pragma unroll
      for (int b = 0; b < 12; ++b) {
        se += we[row * 12 + b] * be[b * KLEN + col];
        si += wi[row * 12 + b] * bi[b * KLEN + col];
        s2 += w2[row * 12 + b] * b2[b * KLEN + col];
      }
      k1e[idx] = se; k1i[idx] = si; k2[idx] = s2;
    }
    return;
  }

  int t0 = bid * 4;
#pragma unroll
  for (int tt = 0; tt < 4; ++tt) {
    int t = t0 + tt;
    const float4* rowE = (const float4*)(S_e + (size_t)t * E_NO);
    float4 a = rowE[tid];
    if (tid < 180) {
      float4 b = rowE[tid + 320];
      a.x += b.x; a.y += b.y; a.z += b.z; a.w += b.w;
    }
    ((float4*)(lds_e + tt * 1280))[tid] = a;
    if (tid < 125) {
      const float4* rowI = (const float4*)(S_i + (size_t)t * I_NO);
      ((float4*)(lds_i + tt * 500))[tid] = rowI[tid];
    }
  }
  __syncthreads();

  // 80 (t,s) pairs x 4 lanes; lane j sums k = 4i+j
  int p = tid >> 2, j = tid & 3;       // p in 0..79
  int tt = p / 20, s = p % 20;
  const float* le = lds_e + tt * 1280 + s;
  const float* li = lds_i + tt * 500 + s;
  float se = 0.f;
#pragma unroll
  for (int i = 0; i < 16; ++i) se += le[20 * (4 * i + j)];
  float sv = 0.f;
#pragma unroll
  for (int i = 0; i < 7; ++i) {
    int k = 4 * i + j;
    if (k < 25) sv += li[20 * k];
  }
  se += __shfl_xor(se, 1); se += __shfl_xor(se, 2);
  sv += __shfl_xor(sv, 1); sv += __shfl_xor(sv, 2);
  if (j == 0)      Se[s * T_DATA + t0 + tt] = se;
  else if (j == 1) Si[s * T_DATA + t0 + tt] = sv;
}

// ---------------------------------------------------------------------------
// conv1: Sconv[s*8+m][t] = sum_d k1e_r[..][d]*Se[s][t-d] + k1i_r[..][d]*Si[s][t-d]
// v3: vectorized LDS staging (aligned-quad shifted reads, b128 writes).
// ---------------------------------------------------------------------------
__global__ __launch_bounds__(256) void conv1_kernel(
    const float* __restrict__ Se, const float* __restrict__ Si,
    const float* __restrict__ k1e, const float* __restrict__ k1i,
    float* __restrict__ Sconv) {
  __shared__ __align__(16) float xe_raw[TW + 4], xi_raw[TW + 4];
  __shared__ __align__(16) float ke[MN * KLEN], ki[MN * KLEN];
  float* xe = xe_raw + 4;   // front pad: last-iter prefetch reads index -4
  float* xi = xi_raw + 4;
  int s = blockIdx.y;
  int t0 = blockIdx.x * TILE;
  int tid = threadIdx.x;

  const float* se_row = Se + (size_t)s * T_DATA;
  const float* si_row = Si + (size_t)s * T_DATA;
  bool fastst = (t0 >= 200) && (t0 + TILE <= T_DATA);
  if (fastst) {
    // 178 quads per signal; idx = 4q..4q+3, t = t0-199+4q (tq-1 aligned)
    for (int q = tid; q < 178; q += 256) {
      int tq = t0 - 199 + 4 * q;
      float4 D = shifted_quad(se_row, tq);
      if (q == 177) D.w = 0.f;                  // idx 711 pad
      *(float4*)(xe + 4 * q) = D;
      D = shifted_quad(si_row, tq);
      if (q == 177) D.w = 0.f;
      *(float4*)(xi + 4 * q) = D;
    }
  } else {
    for (int idx = tid; idx < TW; idx += 256) {
      int t = t0 - HALO + idx;
      bool ok = (t >= 0) && (t < T_DATA) && (idx < 711);
      xe[idx] = ok ? se_row[t] : 0.f;
      xi[idx] = ok ? si_row[t] : 0.f;
    }
  }
  {
    const float4* ge = (const float4*)(k1e + (size_t)s * MN * KLEN);
    const float4* gi = (const float4*)(k1i + (size_t)s * MN * KLEN);
    for (int q = tid; q < 400; q += 256) {
      ((float4*)ke)[q] = ge[q];
      ((float4*)ki)[q] = gi[q];
    }
  }
  __syncthreads();

  int m = tid >> 5, g = tid & 31;
  const float* kem = ke + m * KLEN;
  const float* kim = ki + m * KLEN;
  float* outp = Sconv + ((size_t)(s * MN + m)) * T_DATA + t0;

  float4 Le[4], He[4], Lx[4], Hx[4];
  float acc[4][4];
#pragma unroll
  for (int i = 0; i < 4; ++i) {
    const int S0 = 4 * g + 128 * i + 196;
    Le[i] = *(const float4*)(xe + S0);
    He[i] = *(const float4*)(xe + S0 + 4);
    Lx[i] = *(const float4*)(xi + S0);
    Hx[i] = *(const float4*)(xi + S0 + 4);
    acc[i][0] = acc[i][1] = acc[i][2] = acc[i][3] = 0.f;
  }

  for (int d0 = 0; d0 < KLEN; d0 += 8) {
    float4 ka0 = *(const float4*)(kem + d0);
    float4 kb0 = *(const float4*)(kim + d0);
    float4 ka1 = *(const float4*)(kem + d0 + 4);
    float4 kb1 = *(const float4*)(kim + d0 + 4);
#pragma unroll
    for (int i = 0; i < 4; ++i) {
      const int S0 = 4 * g + 128 * i + 196;
      conv4(acc[i], Le[i], He[i], ka0);
      conv4(acc[i], Lx[i], Hx[i], kb0);
      float4 Ne = *(const float4*)(xe + S0 - d0 - 4);
      float4 Nx = *(const float4*)(xi + S0 - d0 - 4);
      conv4(acc[i], Ne, Le[i], ka1);
      conv4(acc[i], Nx, Lx[i], kb1);
      He[i] = Ne; Le[i] = *(const float4*)(xe + S0 - d0 - 8);
      Hx[i] = Nx; Lx[i] = *(const float4*)(xi + S0 - d0 - 8);
    }
  }

#pragma unroll
  for (int i = 0; i < 4; ++i) {
    const int U = 4 * g + 128 * i;
    if (t0 + U < T_DATA)
      *(float4*)(outp + U) = make_float4(acc[i][0], acc[i][1], acc[i][2], acc[i][3]);
  }
}

// ---------------------------------------------------------------------------
// Level kernel, templated on time-tile (occupancy for small tree levels)
// v3: vectorized hbuf staging + vectorized reduce/output.
// ---------------------------------------------------------------------------
struct LevelArgs {
  int node[10];
  int c1[10];
  int c2[10];
};

template <int LT>
__global__ __launch_bounds__(256) void level_kernel(
    const float* __restrict__ Sconv, const float* __restrict__ k2r,
    const float* __restrict__ leaf_lin, const float* __restrict__ mult_lin,
    const float* __restrict__ mult_bias, float* __restrict__ sub_out,
    float* __restrict__ d_out, LevelArgs args) {
  const int TWL = LT + KLEN;                 // LT+199 used + 1 pad
  constexpr int NT = LT / 128;
  __shared__ __align__(16) float hbuf_raw[4 + MN * (LT + KLEN)];
  __shared__ __align__(16) float k2l[MN * KLEN];
  __shared__ __align__(16) float red[MN * LT];
  float* hbuf = hbuf_raw + 4;
  int tid = threadIdx.x;
  int t0 = blockIdx.x * LT;
  int ni = blockIdx.y;
  int p = args.node[ni], c1 = args.c1[ni], c2 = args.c2[ni];

  {
    const float4* gk = (const float4*)(k2r + (size_t)p * MN * KLEN);
    for (int q = tid; q < 400; q += 256) ((float4*)k2l)[q] = gk[q];
  }

  // h = tanh(Sconv + expL1*child1 + expL2*child2) over tile + halo
  bool fastst = (t0 >= 200) && (t0 + LT <= T_DATA);
  if (fastst) {
    const int QR = TWL / 4;                  // quads per m-row
    const float* s1 = sub_out + (size_t)((c1 >= 0) ? c1 : 0) * T_DATA;
    const float* s2 = sub_out + (size_t)((c2 >= 0) ? c2 : 0) * T_DATA;
    for (int u = tid; u < MN * QR; u += 256) {
      int m = u / QR, q = u - m * QR;
      int tq = t0 - HALO + 4 * q;            // tq-1 aligned, >= 0
      const float* scp = Sconv + ((size_t)(p * MN + m)) * T_DATA;
      float4 X = shifted_quad(scp, tq);
      if (c1 >= 0) {
        float eL1 = __expf(leaf_lin[c1 * MN + m]);
        float4 C = shifted_quad(s1, tq);
        X.x = fmaf(eL1, C.x, X.x); X.y = fmaf(eL1, C.y, X.y);
        X.z = fmaf(eL1, C.z, X.z); X.w = fmaf(eL1, C.w, X.w);
      }
      if (c2 >= 0) {
        float eL2 = __expf(leaf_lin[c2 * MN + m]);
        float4 C = shifted_quad(s2, tq);
        X.x = fmaf(eL2, C.x, X.x); X.y = fmaf(eL2, C.y, X.y);
        X.z = fmaf(eL2, C.z, X.z); X.w = fmaf(eL2, C.w, X.w);
      }
      float4 D = make_float4(fast_tanh(X.x), fast_tanh(X.y),
                             fast_tanh(X.z), fast_tanh(X.w));
      if (q == QR - 1) D.w = 0.f;            // pad element idx = TWL-1
      *(float4*)(hbuf + m * TWL + 4 * q) = D;
    }
  } else {
    for (int m = 0; m < MN; ++m) {
      float eL1 = (c1 >= 0) ? __expf(leaf_lin[c1 * MN + m]) : 0.f;
      float eL2 = (c2 >= 0) ? __expf(leaf_lin[c2 * MN + m]) : 0.f;
      const float* scp = Sconv + ((size_t)(p * MN + m)) * T_DATA;
      const float* s1 = sub_out + (size_t)((c1 >= 0) ? c1 : 0) * T_DATA;
      const float* s2 = sub_out + (size_t)((c2 >= 0) ? c2 : 0) * T_DATA;
      for (int idx = tid; idx < TWL; idx += 256) {
        int t = t0 - HALO + idx;
        float v = 0.f;
        if (t >= 0 && t < T_DATA && idx < TWL - 1) {
          float x = scp[t];
          if (c1 >= 0) x += eL1 * s1[t];
          if (c2 >= 0) x += eL2 * s2[t];
          v = fast_tanh(x);
        }
        hbuf[m * TWL + idx] = v;
      }
    }
  }
  __syncthreads();

  // depthwise causal conv-200, conflict-free lane mapping + sliding window
  int m = tid >> 5, g = tid & 31;
  const float* km = k2l + m * KLEN;
  const float* hm = hbuf + m * TWL;
  float eM = __expf(mult_lin[p * MN + m]);

  float4 L[NT], H[NT];
  float acc[NT][4];
#pragma unroll
  for (int i = 0; i < NT; ++i) {
    const int S0 = 4 * g + 128 * i + 196;
    L[i] = *(const float4*)(hm + S0);
    H[i] = *(const float4*)(hm + S0 + 4);
    acc[i][0] = acc[i][1] = acc[i][2] = acc[i][3] = 0.f;
  }
  for (int d0 = 0; d0 < KLEN; d0 += 8) {
    float4 ka0 = *(const float4*)(km + d0);
    float4 ka1 = *(const float4*)(km + d0 + 4);
#pragma unroll
    for (int i = 0; i < NT; ++i) {
      const int S0 = 4 * g + 128 * i + 196;
      conv4(acc[i], L[i], H[i], ka0);
      float4 N = *(const float4*)(hm + S0 - d0 - 4);
      conv4(acc[i], N, L[i], ka1);
      H[i] = N; L[i] = *(const float4*)(hm + S0 - d0 - 8);
    }
  }
#pragma unroll
  for (int i = 0; i < NT; ++i) {
    const int U = 4 * g + 128 * i;
    *(float4*)(red + m * LT + U) =
        make_float4(fast_tanh(acc[i][0]) * eM, fast_tanh(acc[i][1]) * eM,
                    fast_tanh(acc[i][2]) * eM, fast_tanh(acc[i][3]) * eM);
  }
  __syncthreads();

  // reduce over m, add bias, write (vectorized fast path)
  float bias = mult_bias[p];
  float* outp = (p == 0) ? d_out : (sub_out + (size_t)p * T_DATA);
  if (t0 + LT <= T_DATA) {
    if (tid < LT / 4) {
      float4 ssum = make_float4(bias, bias, bias, bias);
#pragma unroll
      for (int mm = 0; mm < MN; ++mm) {
        float4 r = *(const float4*)(red + mm * LT + 4 * tid);
        ssum.x += r.x; ssum.y += r.y; ssum.z += r.z; ssum.w += r.w;
      }
      *(float4*)(outp + t0 + 4 * tid) = ssum;
    }
  } else {
#pragma unroll
    for (int k = 0; k < (LT + 255) / 256; ++k) {
      int tl2 = tid + k * 256;
      if (tl2 < LT) {
        int t = t0 + tl2;
        if (t < T_DATA) {
          float ssum = bias;
#pragma unroll
          for (int mm = 0; mm < MN; ++mm) ssum += red[mm * LT + tl2];
          outp[t] = ssum;
        }
      }
    }
  }
}

// ---------------------------------------------------------------------------
extern "C" void kernel_launch(void* const* d_in, const int* in_sizes, int n_in,
                              void* d_out, int out_size, void* d_ws, size_t ws_size,
                              hipStream_t stream) {
  const float* S_e  = (const float*)d_in[0];
  const float* S_i  = (const float*)d_in[1];
  const float* c1eb = (const float*)d_in[5];
  const float* c1ew = (const float*)d_in[6];
  const float* c1ib = (const float*)d_in[7];
  const float* c1iw = (const float*)d_in[8];
  const float* c2b  = (const float*)d_in[9];
  const float* c2w  = (const float*)d_in[10];
  const float* ll   = (const float*)d_in[11];
  const float* ml   = (const float*)d_in[12];
  const float* mb   = (const float*)d_in[13];

  float* ws    = (float*)d_ws;
  float* Se    = ws;                 // 1,000,000
  float* Si    = ws + 1000000;       // 1,000,000
  float* Sconv = ws + 2000000;       // 8,000,000
  float* subo  = ws + 10000000;      // 1,000,000
  float* k1e   = ws + 11000000;      // 32,000
  float* k1i   = k1e + 32000;        // 32,000
  float* k2    = k1i + 32000;        // 32,000
  float* out   = (float*)d_out;

  // routing + kernel precompute fused (12500 route blocks + 100 precompute)
  route_kernel<<<dim3(12600), 320, 0, stream>>>(S_e, S_i, Se, Si,
                                                c1ew, c1eb, c1iw, c1ib, c2w, c2b,
                                                k1e, k1i, k2);

  conv1_kernel<<<dim3(98, SUBN), 256, 0, stream>>>(Se, Si, k1e, k1i, Sconv);

  // Stage A: ALL dependency-free leaves (10 nodes -> 1960 blocks, fat launch)
  LevelArgs LA = {{10, 11, 12, 13, 14, 15, 16, 17, 18, 19},
                  {-1, -1, -1, -1, -1, -1, -1, -1, -1, -1},
                  {-1, -1, -1, -1, -1, -1, -1, -1, -1, -1}};
  LevelArgs LB = {{7, 8, 9, 0, 0, 0, 0, 0, 0, 0},
                  {15, 17, 19, 0, 0, 0, 0, 0, 0, 0},
                  {16, 18, -1, 0, 0, 0, 0, 0, 0, 0}};
  LevelArgs LC = {{3, 4, 5, 6, 0, 0, 0, 0, 0, 0},
                  {7, 9, 11, 13, 0, 0, 0, 0, 0, 0},
                  {8, 10, 12, 14, 0, 0, 0, 0, 0, 0}};
  LevelArgs LD = {{1, 2, 0, 0, 0, 0, 0, 0, 0, 0},
                  {3, 5, 0, 0, 0, 0, 0, 0, 0, 0},
                  {4, 6, 0, 0, 0, 0, 0, 0, 0, 0}};
  LevelArgs LE = {{0, 0, 0, 0, 0, 0, 0, 0, 0, 0},
                  {1, 0, 0, 0, 0, 0, 0, 0, 0, 0},
                  {2, 0, 0, 0, 0, 0, 0, 0, 0, 0}};

  level_kernel<256><<<dim3(196, 10), 256, 0, stream>>>(Sconv, k2, ll, ml, mb, subo, out, LA);
  level_kernel<256><<<dim3(196, 3),  256, 0, stream>>>(Sconv, k2, ll, ml, mb, subo, out, LB);
  level_kernel<128><<<dim3(391, 4),  256, 0, stream>>>(Sconv, k2, ll, ml, mb, subo, out, LC);
  level_kernel<128><<<dim3(391, 2),  256, 0, stream>>>(Sconv, k2, ll, ml, mb, subo, out, LD);
  level_kernel<128><<<dim3(391, 1),  256, 0, stream>>>(Sconv, k2, ll, ml, mb, subo, out, LE);
}